// Round 3
// baseline (115.037 us; speedup 1.0000x reference)
//
#include <hip/hip_runtime.h>
#include <hip/hip_bf16.h>

// Problem: SEQ=192, BATCH=2, C_P=128, C=32, C_I=128
// out[b,k,i,j] = ( sum_{c,d} p1[b,i,c] p2[b,j,d] Wk[k,c,d] + bout[k] ) / 2
// p1 = LN(p) @ W1^T + b1 ; p2 = LN(p) @ W2^T + b2 ; Wk = Wout.reshape(128,32,32)
//
// Single fused kernel. Grid = (b, k, iq) = 1024 blocks x 256 threads.
// Per block (all redundant per (b,k,iq), by design — pre-work is cheap):
//   1. LN stats (mu, rsqrt) per row, thread-per-row.
//   2. k-tiled projection: stage pn[:, 32-wide] bf16 slab in LDS, MFMA
//      pn @ W2 (scaled by 0.5 = the /B fold) into regs; wave iq also does
//      pn @ W1 for its 48 i-rows. Biases folded into acc init.
//   3. p2 -> LDS (all 192 rows), p1 -> LDS (48 rows).
//   4. T2^T[j][c] = sum_d p2[j][d] Wk[c][d] via MFMA -> LDS (overlay slab).
//   5. out[i0..i0+47, :] = p1 @ T2^T + 0.5*bout[k], direct f32 stores.
// Waves own disjoint 48-row j-ranges in 4/5, so no barrier between them.

#define SEQ 192
#define BATCH 2
#define CP 128
#define CDIM 32
#define CI 128
#define PAD 40   // LDS row stride in bf16 elems

typedef __attribute__((ext_vector_type(8))) short bf16x8;   // 8 bf16 = 4 VGPRs
typedef __attribute__((ext_vector_type(4))) float f32x4;

static __device__ __forceinline__ short f2bf(float f) {
    unsigned u = __builtin_bit_cast(unsigned, f);
    u += 0x7fffu + ((u >> 16) & 1u);   // round-to-nearest-even
    return (short)(u >> 16);
}

__global__ __launch_bounds__(256, 4) void opm_fused(
    const float* __restrict__ p, const float* __restrict__ gamma,
    const float* __restrict__ beta, const float* __restrict__ W1,
    const float* __restrict__ b1, const float* __restrict__ W2,
    const float* __restrict__ b2, const float* __restrict__ Wout,
    const float* __restrict__ bout, float* __restrict__ out)
{
    int bk = blockIdx.x >> 2;         // b*CI + k
    int iq = blockIdx.x & 3;          // 48-row i chunk
    int b = bk >> 7, k = bk & 127;
    int tid  = threadIdx.x;
    int wave = tid >> 6, lane = tid & 63;
    int l15  = lane & 15, quad = lane >> 4;

    __shared__ float mu_s[SEQ];
    __shared__ float rs_s[SEQ];
    __shared__ short slab[SEQ * PAD];   // pn k-slab; later overlaid by T2^T
    __shared__ short p2s[SEQ * PAD];    // p2 (0.5-scaled), [j][d]
    __shared__ short p1s[48 * PAD];     // p1 rows for this block's i chunk

    // ---- 1. LN stats, thread-per-row ----
    if (tid < SEQ) {
        const float4* pr = (const float4*)(p + tid * (BATCH * CP) + b * CP);
        float s1 = 0.0f, s2 = 0.0f;
        #pragma unroll
        for (int i = 0; i < CP / 4; ++i) {
            float4 v = pr[i];
            s1 += v.x + v.y + v.z + v.w;
            s2 += v.x * v.x + v.y * v.y + v.z * v.z + v.w * v.w;
        }
        float mu  = s1 * (1.0f / CP);
        float var = s2 * (1.0f / CP) - mu * mu;
        mu_s[tid] = mu;
        rs_s[tid] = rsqrtf(var + 1e-5f);
    }
    __syncthreads();

    // ---- 2. projection: acc[mi][nt], C/D layout col=l15 (n), row=quad*4+r ----
    bool doP1 = (wave == iq);
    f32x4 accP2[3][2], accP1[3][2];
    #pragma unroll
    for (int mi = 0; mi < 3; ++mi)
        #pragma unroll
        for (int nt = 0; nt < 2; ++nt) {
            float v2 = 0.5f * b2[nt * 16 + l15];
            float v1 = b1[nt * 16 + l15];
            accP2[mi][nt] = (f32x4){v2, v2, v2, v2};
            accP1[mi][nt] = (f32x4){v1, v1, v1, v1};
        }

    int r0 = tid >> 3, c4 = (tid & 7) * 4;   // slab-build mapping
    for (int kt = 0; kt < 4; ++kt) {
        // stage pn[:, kt*32 .. kt*32+31] as bf16 into slab
        float4 g4  = *(const float4*)(gamma + kt * 32 + c4);
        float4 be4 = *(const float4*)(beta  + kt * 32 + c4);
        #pragma unroll
        for (int pp = 0; pp < 6; ++pp) {
            int row = pp * 32 + r0;
            float4 v = *(const float4*)(p + row * (BATCH * CP) + b * CP + kt * 32 + c4);
            float mu = mu_s[row], rs = rs_s[row];
            short4 o;
            o.x = f2bf((v.x - mu) * rs * g4.x + be4.x);
            o.y = f2bf((v.y - mu) * rs * g4.y + be4.y);
            o.z = f2bf((v.z - mu) * rs * g4.z + be4.z);
            o.w = f2bf((v.w - mu) * rs * g4.w + be4.w);
            *(short4*)(slab + row * PAD + c4) = o;
        }
        __syncthreads();

        // MFMA accumulate over this k-tile
        #pragma unroll
        for (int mi = 0; mi < 3; ++mi) {
            int i0 = (wave * 3 + mi) * 16;
            bf16x8 af = *(const bf16x8*)(slab + (i0 + l15) * PAD + quad * 8);
            #pragma unroll
            for (int nt = 0; nt < 2; ++nt) {
                const float* w = W2 + (nt * 16 + l15) * CP + kt * 32 + quad * 8;
                bf16x8 bf;
                #pragma unroll
                for (int e = 0; e < 8; ++e) bf[e] = f2bf(0.5f * w[e]);
                accP2[mi][nt] = __builtin_amdgcn_mfma_f32_16x16x32_bf16(
                    af, bf, accP2[mi][nt], 0, 0, 0);
            }
            if (doP1) {
                #pragma unroll
                for (int nt = 0; nt < 2; ++nt) {
                    const float* w = W1 + (nt * 16 + l15) * CP + kt * 32 + quad * 8;
                    bf16x8 bf;
                    #pragma unroll
                    for (int e = 0; e < 8; ++e) bf[e] = f2bf(w[e]);
                    accP1[mi][nt] = __builtin_amdgcn_mfma_f32_16x16x32_bf16(
                        af, bf, accP1[mi][nt], 0, 0, 0);
                }
            }
        }
        __syncthreads();   // protect slab before next stage
    }

    // ---- 3. write p2 (all waves) and p1 (wave iq) to LDS ----
    #pragma unroll
    for (int mi = 0; mi < 3; ++mi) {
        int i0 = (wave * 3 + mi) * 16;
        #pragma unroll
        for (int nt = 0; nt < 2; ++nt)
            #pragma unroll
            for (int r = 0; r < 4; ++r)
                p2s[(i0 + quad * 4 + r) * PAD + nt * 16 + l15] =
                    f2bf(accP2[mi][nt][r]);
    }
    if (doP1) {
        #pragma unroll
        for (int mi = 0; mi < 3; ++mi)
            #pragma unroll
            for (int nt = 0; nt < 2; ++nt)
                #pragma unroll
                for (int r = 0; r < 4; ++r)
                    p1s[(mi * 16 + quad * 4 + r) * PAD + nt * 16 + l15] =
                        f2bf(accP1[mi][nt][r]);
    }
    __syncthreads();   // p1s visible to all waves; slab readers all done

    // ---- 4. T2^T[j][c] via MFMA, wave-private j range, into slab ----
    const float* wk = Wout + k * (CDIM * CDIM);
    bf16x8 bfr[2];
    #pragma unroll
    for (int ni = 0; ni < 2; ++ni) {
        const float* wrow = wk + (ni * 16 + l15) * CDIM + quad * 8;
        #pragma unroll
        for (int e = 0; e < 8; ++e) bfr[ni][e] = f2bf(wrow[e]);
    }
    #pragma unroll
    for (int mi = 0; mi < 3; ++mi) {
        int j0 = (wave * 3 + mi) * 16;
        bf16x8 af = *(const bf16x8*)(p2s + (j0 + l15) * PAD + quad * 8);
        #pragma unroll
        for (int ni = 0; ni < 2; ++ni) {
            f32x4 acc = {0.0f, 0.0f, 0.0f, 0.0f};
            acc = __builtin_amdgcn_mfma_f32_16x16x32_bf16(af, bfr[ni], acc, 0, 0, 0);
            #pragma unroll
            for (int r = 0; r < 4; ++r)
                slab[(j0 + quad * 4 + r) * PAD + ni * 16 + l15] = f2bf(acc[r]);
        }
    }
    // no barrier: phase 5 reads only this wave's own t2 rows (lgkmcnt orders)

    // ---- 5. out tile: 48 i-rows x 48 j-cols per wave ----
    float biask = 0.5f * bout[k];
    float* obase = out + (size_t)bk * (SEQ * SEQ);
    #pragma unroll
    for (int ii = 0; ii < 3; ++ii) {
        int i0 = iq * 48 + ii * 16;
        bf16x8 af = *(const bf16x8*)(p1s + (ii * 16 + l15) * PAD + quad * 8);
        #pragma unroll
        for (int jj = 0; jj < 3; ++jj) {
            int j0 = (wave * 3 + jj) * 16;
            bf16x8 bf = *(const bf16x8*)(slab + (j0 + l15) * PAD + quad * 8);
            f32x4 acc = {biask, biask, biask, biask};
            acc = __builtin_amdgcn_mfma_f32_16x16x32_bf16(af, bf, acc, 0, 0, 0);
            float* o = obase + (i0 + quad * 4) * SEQ + j0 + l15;
            #pragma unroll
            for (int r = 0; r < 4; ++r)
                o[r * SEQ] = acc[r];
        }
    }
}

extern "C" void kernel_launch(void* const* d_in, const int* in_sizes, int n_in,
                              void* d_out, int out_size, void* d_ws, size_t ws_size,
                              hipStream_t stream) {
    const float* p     = (const float*)d_in[0];
    const float* gamma = (const float*)d_in[1];
    const float* beta  = (const float*)d_in[2];
    const float* W1    = (const float*)d_in[3];
    const float* b1    = (const float*)d_in[4];
    const float* W2    = (const float*)d_in[5];
    const float* b2    = (const float*)d_in[6];
    const float* Wout  = (const float*)d_in[7];
    const float* bout  = (const float*)d_in[8];
    float* out = (float*)d_out;

    opm_fused<<<BATCH * CI * 4, 256, 0, stream>>>(
        p, gamma, beta, W1, b1, W2, b2, Wout, bout, out);
}

// Round 4
// 89.162 us; speedup vs baseline: 1.2902x; 1.2902x over previous
//
#include <hip/hip_runtime.h>
#include <hip/hip_bf16.h>

// Problem: SEQ=192, BATCH=2, C_P=128, C=32, C_I=128
// out[b,k,i,j] = ( sum_{c,d} p1[b,i,c] p2[b,j,d] Wk[k,c,d] + bout[k] ) / 2
// p1 = LN(p) @ W1^T + b1 ; p2 = LN(p) @ W2^T + b2 ; Wk = Wout.reshape(128,32,32)
//
// Two kernels (round-2 structure; round-3 full fusion regressed):
//   opm_pre : per (s,b) row LN + dual projection in f32, bf16 outputs to ws.
//             First 128 blocks also convert Wout row k -> bf16 in ws.
//   opm_main: per (b,k,iq) block: T2^T via MFMA (Wk frags now direct bf16x8
//             vector loads), then 48x192 output tile, direct f32 stores.

#define SEQ 192
#define BATCH 2
#define CP 128
#define CDIM 32
#define CI 128

typedef __attribute__((ext_vector_type(8))) short bf16x8;   // 8 bf16 = 4 VGPRs
typedef __attribute__((ext_vector_type(4))) float f32x4;

static __device__ __forceinline__ short f2bf(float f) {
    unsigned u = __builtin_bit_cast(unsigned, f);
    u += 0x7fffu + ((u >> 16) & 1u);   // round-to-nearest-even
    return (short)(u >> 16);
}

// ---------------------------------------------------------------------------
// Kernel A: fused LayerNorm + dual projection (f32 math), one block per (s,b).
// p2 pre-scaled by 0.5 (the /B fold). Blocks 0..127 also convert Wout k-row
// to bf16 (layout-preserving) for opm_main's direct B-fragment loads.
// ---------------------------------------------------------------------------
__global__ __launch_bounds__(128) void opm_pre(
    const float* __restrict__ p, const float* __restrict__ gamma,
    const float* __restrict__ beta, const float* __restrict__ W1,
    const float* __restrict__ b1, const float* __restrict__ W2,
    const float* __restrict__ b2, const float* __restrict__ Wout,
    short* __restrict__ p1ws, short* __restrict__ p2ws,
    short* __restrict__ wkbf)
{
    int row = blockIdx.x;          // s*BATCH + b
    int s = row >> 1, b = row & 1;
    int t = threadIdx.x;

    // Wout row conversion (blocks 0..127 = k)
    if (row < CI) {
        const float4* src = (const float4*)(Wout + row * (CDIM * CDIM)) + t * 2;
        float4 a = src[0], c = src[1];
        short4 o0, o1;
        o0.x = f2bf(a.x); o0.y = f2bf(a.y); o0.z = f2bf(a.z); o0.w = f2bf(a.w);
        o1.x = f2bf(c.x); o1.y = f2bf(c.y); o1.z = f2bf(c.z); o1.w = f2bf(c.w);
        short4* dst = (short4*)(wkbf + row * (CDIM * CDIM)) + t * 2;
        dst[0] = o0; dst[1] = o1;
    }

    __shared__ float pns[CP];
    __shared__ float red[4];
    __shared__ float part[CP];

    float x = p[s * (BATCH * CP) + b * CP + t];
    float s1 = x, s2 = x * x;
    #pragma unroll
    for (int off = 32; off; off >>= 1) {
        s1 += __shfl_down(s1, off);
        s2 += __shfl_down(s2, off);
    }
    int wave = t >> 6, lane = t & 63;
    if (lane == 0) { red[wave * 2] = s1; red[wave * 2 + 1] = s2; }
    __syncthreads();
    float tot  = red[0] + red[2];
    float tot2 = red[1] + red[3];
    float mu  = tot * (1.0f / CP);
    float var = tot2 * (1.0f / CP) - mu * mu;
    float rs  = rsqrtf(var + 1e-5f);
    pns[t] = (x - mu) * rs * gamma[t] + beta[t];
    __syncthreads();

    // 64 dot products of length 128, split in halves across 128 threads.
    int c = t & 63, half = t >> 6;
    const float* wrow = (c < CDIM ? W1 + c * CP : W2 + (c - CDIM) * CP) + half * 64;
    const float4* pn4 = (const float4*)(pns + half * 64);
    const float4* w4p = (const float4*)wrow;
    float acc = 0.0f;
    #pragma unroll
    for (int i = 0; i < 16; ++i) {
        float4 w4 = w4p[i];
        float4 pn = pn4[i];
        acc += w4.x * pn.x + w4.y * pn.y + w4.z * pn.z + w4.w * pn.w;
    }
    part[t] = acc;
    __syncthreads();
    if (t < 64) {
        float d = part[t] + part[t + 64];
        if (c < CDIM) {
            p1ws[(b * SEQ + s) * CDIM + c] = f2bf(d + b1[c]);
        } else {
            p2ws[(b * SEQ + s) * CDIM + (c - CDIM)] =
                f2bf(0.5f * (d + b2[c - CDIM]));
        }
    }
}

// ---------------------------------------------------------------------------
// Kernel B: one block per (b, k, i-chunk of 48). 4 waves, 256 threads.
// Phase 1: wave w builds T2^T rows j in [48w, 48w+48) via MFMA into LDS.
// Phase 2: wave w computes out[i0..i0+47, 48w..48w+47] — reads ONLY its own
//   T2 rows, so no __syncthreads (intra-wave lgkmcnt ordering suffices).
// ---------------------------------------------------------------------------
#define T2PAD 40   // row stride in bf16 elems

__global__ __launch_bounds__(256) void opm_main(
    const short* __restrict__ p1ws,   // [B][SEQ][32] bf16
    const short* __restrict__ p2ws,   // [B][SEQ][32] bf16 (pre-scaled 0.5)
    const short* __restrict__ wkbf,   // [128][32][32] bf16
    const float* __restrict__ bout,   // [128]
    float* __restrict__ out)          // [B][128][192][192]
{
    int bk = blockIdx.x >> 2;         // b*CI + k
    int iq = blockIdx.x & 3;          // which 48-row i chunk
    int b = bk >> 7, k = bk & 127;
    int tid  = threadIdx.x;
    int wave = tid >> 6, lane = tid & 63;
    int l15  = lane & 15, quad = lane >> 4;

    __shared__ short t2s[SEQ * T2PAD];

    // ---- Phase 1: T2^T (M=j, N=c=32, K=d=32), wave-private j range ----
    const short* wkb = wkbf + k * (CDIM * CDIM);
    bf16x8 bfr0 = *(const bf16x8*)(wkb + l15 * CDIM + quad * 8);
    bf16x8 bfr1 = *(const bf16x8*)(wkb + (16 + l15) * CDIM + quad * 8);
    #pragma unroll
    for (int mi = 0; mi < 3; ++mi) {
        int j0 = (wave * 3 + mi) * 16;
        bf16x8 afrag = *(const bf16x8*)(p2ws + (b * SEQ + j0 + l15) * CDIM + quad * 8);
        f32x4 acc0 = {0.0f, 0.0f, 0.0f, 0.0f};
        f32x4 acc1 = {0.0f, 0.0f, 0.0f, 0.0f};
        acc0 = __builtin_amdgcn_mfma_f32_16x16x32_bf16(afrag, bfr0, acc0, 0, 0, 0);
        acc1 = __builtin_amdgcn_mfma_f32_16x16x32_bf16(afrag, bfr1, acc1, 0, 0, 0);
        #pragma unroll
        for (int r = 0; r < 4; ++r) {
            t2s[(j0 + quad * 4 + r) * T2PAD + l15]      = f2bf(acc0[r]);
            t2s[(j0 + quad * 4 + r) * T2PAD + 16 + l15] = f2bf(acc1[r]);
        }
    }

    // ---- Phase 2: out tile (M=i 48 rows, N=j 48 cols/wave, K=c=32) ----
    float biask = 0.5f * bout[k];
    const short* p1b = p1ws + b * SEQ * CDIM;
    float* obase = out + (size_t)bk * (SEQ * SEQ);
    #pragma unroll
    for (int ii = 0; ii < 3; ++ii) {
        int i0 = iq * 48 + ii * 16;
        bf16x8 afrag = *(const bf16x8*)(p1b + (i0 + l15) * CDIM + quad * 8);
        #pragma unroll
        for (int jj = 0; jj < 3; ++jj) {
            int j0 = (wave * 3 + jj) * 16;
            bf16x8 bfrag = *(const bf16x8*)(t2s + (j0 + l15) * T2PAD + quad * 8);
            f32x4 acc = {biask, biask, biask, biask};
            acc = __builtin_amdgcn_mfma_f32_16x16x32_bf16(afrag, bfrag, acc, 0, 0, 0);
            float* o = obase + (i0 + quad * 4) * SEQ + j0 + l15;
            #pragma unroll
            for (int r = 0; r < 4; ++r)
                o[r * SEQ] = acc[r];
        }
    }
}

extern "C" void kernel_launch(void* const* d_in, const int* in_sizes, int n_in,
                              void* d_out, int out_size, void* d_ws, size_t ws_size,
                              hipStream_t stream) {
    const float* p     = (const float*)d_in[0];
    const float* gamma = (const float*)d_in[1];
    const float* beta  = (const float*)d_in[2];
    const float* W1    = (const float*)d_in[3];
    const float* b1    = (const float*)d_in[4];
    const float* W2    = (const float*)d_in[5];
    const float* b2    = (const float*)d_in[6];
    const float* Wout  = (const float*)d_in[7];
    const float* bout  = (const float*)d_in[8];
    float* out = (float*)d_out;

    short* p1ws = (short*)d_ws;                      // 2*192*32 bf16
    short* p2ws = p1ws + BATCH * SEQ * CDIM;         // 2*192*32 bf16
    short* wkbf = p2ws + BATCH * SEQ * CDIM;         // 128*1024 bf16

    opm_pre<<<SEQ * BATCH, 128, 0, stream>>>(p, gamma, beta, W1, b1, W2, b2,
                                             Wout, p1ws, p2ws, wkbf);
    opm_main<<<BATCH * CI * 4, 256, 0, stream>>>(p1ws, p2ws, wkbf, bout, out);
}

// Round 5
// 87.504 us; speedup vs baseline: 1.3147x; 1.0190x over previous
//
#include <hip/hip_runtime.h>
#include <hip/hip_bf16.h>

// Problem: SEQ=192, BATCH=2, C_P=128, C=32, C_I=128
// out[b,k,i,j] = ( sum_{c,d} p1[b,i,c] p2[b,j,d] Wk[k,c,d] + bout[k] ) / 2
// p1 = LN(p) @ W1^T + b1 ; p2 = LN(p) @ W2^T + b2 ; Wk = Wout.reshape(128,32,32)
//
// Two kernels:
//   opm_pre : per (s,b) row LN + dual projection in f32, bf16 outputs to ws.
//             First 128 blocks also convert Wout row k -> bf16 in ws.
//   opm_main: per (b,k,iq) block (iq = 32-row i chunk, 6 per bk -> 1536
//             blocks, 6 blocks/CU for latency hiding): T2^T via MFMA into
//             LDS (wave-private j range, no barrier), then 32x192 out tile.

#define SEQ 192
#define BATCH 2
#define CP 128
#define CDIM 32
#define CI 128

typedef __attribute__((ext_vector_type(8))) short bf16x8;   // 8 bf16 = 4 VGPRs
typedef __attribute__((ext_vector_type(4))) float f32x4;

static __device__ __forceinline__ short f2bf(float f) {
    unsigned u = __builtin_bit_cast(unsigned, f);
    u += 0x7fffu + ((u >> 16) & 1u);   // round-to-nearest-even
    return (short)(u >> 16);
}

// ---------------------------------------------------------------------------
__global__ __launch_bounds__(128) void opm_pre(
    const float* __restrict__ p, const float* __restrict__ gamma,
    const float* __restrict__ beta, const float* __restrict__ W1,
    const float* __restrict__ b1, const float* __restrict__ W2,
    const float* __restrict__ b2, const float* __restrict__ Wout,
    short* __restrict__ p1ws, short* __restrict__ p2ws,
    short* __restrict__ wkbf)
{
    int row = blockIdx.x;          // s*BATCH + b
    int s = row >> 1, b = row & 1;
    int t = threadIdx.x;

    // Wout row conversion (blocks 0..127 = k), layout-preserving f32->bf16
    if (row < CI) {
        const float4* src = (const float4*)(Wout + row * (CDIM * CDIM)) + t * 2;
        float4 a = src[0], c = src[1];
        short4 o0, o1;
        o0.x = f2bf(a.x); o0.y = f2bf(a.y); o0.z = f2bf(a.z); o0.w = f2bf(a.w);
        o1.x = f2bf(c.x); o1.y = f2bf(c.y); o1.z = f2bf(c.z); o1.w = f2bf(c.w);
        short4* dst = (short4*)(wkbf + row * (CDIM * CDIM)) + t * 2;
        dst[0] = o0; dst[1] = o1;
    }

    __shared__ float pns[CP];
    __shared__ float red[4];
    __shared__ float part[CP];

    float x = p[s * (BATCH * CP) + b * CP + t];
    float s1 = x, s2 = x * x;
    #pragma unroll
    for (int off = 32; off; off >>= 1) {
        s1 += __shfl_down(s1, off);
        s2 += __shfl_down(s2, off);
    }
    int wave = t >> 6, lane = t & 63;
    if (lane == 0) { red[wave * 2] = s1; red[wave * 2 + 1] = s2; }
    __syncthreads();
    float tot  = red[0] + red[2];
    float tot2 = red[1] + red[3];
    float mu  = tot * (1.0f / CP);
    float var = tot2 * (1.0f / CP) - mu * mu;
    float rs  = rsqrtf(var + 1e-5f);
    pns[t] = (x - mu) * rs * gamma[t] + beta[t];
    __syncthreads();

    // 64 dot products of length 128, split in halves across 128 threads.
    int c = t & 63, half = t >> 6;
    const float* wrow = (c < CDIM ? W1 + c * CP : W2 + (c - CDIM) * CP) + half * 64;
    const float4* pn4 = (const float4*)(pns + half * 64);
    const float4* w4p = (const float4*)wrow;
    float acc = 0.0f;
    #pragma unroll
    for (int i = 0; i < 16; ++i) {
        float4 w4 = w4p[i];
        float4 pn = pn4[i];
        acc += w4.x * pn.x + w4.y * pn.y + w4.z * pn.z + w4.w * pn.w;
    }
    part[t] = acc;
    __syncthreads();
    if (t < 64) {
        float d = part[t] + part[t + 64];
        if (c < CDIM) {
            p1ws[(b * SEQ + s) * CDIM + c] = f2bf(d + b1[c]);
        } else {
            p2ws[(b * SEQ + s) * CDIM + (c - CDIM)] =
                f2bf(0.5f * (d + b2[c - CDIM]));
        }
    }
}

// ---------------------------------------------------------------------------
// One block per (b, k, iq) with iq = 32-row i chunk (6 per bk). 4 waves.
// Phase 1: wave w builds T2^T rows j in [48w, 48w+48) via MFMA into LDS.
// Phase 2: wave w computes out[i0..i0+31, 48w..48w+47] — reads ONLY its own
//   T2 rows, so no __syncthreads (intra-wave lgkmcnt ordering suffices).
// All global fragment loads hoisted to entry for max vmcnt overlap.
// ---------------------------------------------------------------------------
#define T2PAD 40   // row stride in bf16 elems

__global__ __launch_bounds__(256) void opm_main(
    const short* __restrict__ p1ws,   // [B][SEQ][32] bf16
    const short* __restrict__ p2ws,   // [B][SEQ][32] bf16 (pre-scaled 0.5)
    const short* __restrict__ wkbf,   // [128][32][32] bf16
    const float* __restrict__ bout,   // [128]
    float* __restrict__ out)          // [B][128][192][192]
{
    int bk = blockIdx.x / 6;          // b*CI + k
    int iq = blockIdx.x - bk * 6;     // which 32-row i chunk
    int b = bk >> 7, k = bk & 127;
    int tid  = threadIdx.x;
    int wave = tid >> 6, lane = tid & 63;
    int l15  = lane & 15, quad = lane >> 4;

    __shared__ short t2s[SEQ * T2PAD];

    // ---- hoisted global loads (independent; vmcnt covers the whole chain) --
    const short* wkb = wkbf + k * (CDIM * CDIM);
    bf16x8 bfr0 = *(const bf16x8*)(wkb + l15 * CDIM + quad * 8);
    bf16x8 bfr1 = *(const bf16x8*)(wkb + (16 + l15) * CDIM + quad * 8);
    bf16x8 a2[3];
    #pragma unroll
    for (int mi = 0; mi < 3; ++mi) {
        int j0 = (wave * 3 + mi) * 16;
        a2[mi] = *(const bf16x8*)(p2ws + (b * SEQ + j0 + l15) * CDIM + quad * 8);
    }
    const short* p1b = p1ws + b * SEQ * CDIM;
    bf16x8 a1[2];
    #pragma unroll
    for (int ii = 0; ii < 2; ++ii) {
        int i0 = iq * 32 + ii * 16;
        a1[ii] = *(const bf16x8*)(p1b + (i0 + l15) * CDIM + quad * 8);
    }
    float biask = 0.5f * bout[k];

    // ---- Phase 1: T2^T (M=j, N=c=32, K=d=32), wave-private j range ----
    #pragma unroll
    for (int mi = 0; mi < 3; ++mi) {
        int j0 = (wave * 3 + mi) * 16;
        f32x4 acc0 = {0.0f, 0.0f, 0.0f, 0.0f};
        f32x4 acc1 = {0.0f, 0.0f, 0.0f, 0.0f};
        acc0 = __builtin_amdgcn_mfma_f32_16x16x32_bf16(a2[mi], bfr0, acc0, 0, 0, 0);
        acc1 = __builtin_amdgcn_mfma_f32_16x16x32_bf16(a2[mi], bfr1, acc1, 0, 0, 0);
        #pragma unroll
        for (int r = 0; r < 4; ++r) {
            t2s[(j0 + quad * 4 + r) * T2PAD + l15]      = f2bf(acc0[r]);
            t2s[(j0 + quad * 4 + r) * T2PAD + 16 + l15] = f2bf(acc1[r]);
        }
    }

    // ---- Phase 2: out tile (M=i 32 rows, N=j 48 cols/wave, K=c=32) ----
    float* obase = out + (size_t)bk * (SEQ * SEQ);
    #pragma unroll
    for (int ii = 0; ii < 2; ++ii) {
        int i0 = iq * 32 + ii * 16;
        #pragma unroll
        for (int jj = 0; jj < 3; ++jj) {
            int j0 = (wave * 3 + jj) * 16;
            bf16x8 bfrag = *(const bf16x8*)(t2s + (j0 + l15) * T2PAD + quad * 8);
            f32x4 acc = {biask, biask, biask, biask};
            acc = __builtin_amdgcn_mfma_f32_16x16x32_bf16(a1[ii], bfrag, acc, 0, 0, 0);
            float* o = obase + (i0 + quad * 4) * SEQ + j0 + l15;
            #pragma unroll
            for (int r = 0; r < 4; ++r)
                o[r * SEQ] = acc[r];
        }
    }
}

extern "C" void kernel_launch(void* const* d_in, const int* in_sizes, int n_in,
                              void* d_out, int out_size, void* d_ws, size_t ws_size,
                              hipStream_t stream) {
    const float* p     = (const float*)d_in[0];
    const float* gamma = (const float*)d_in[1];
    const float* beta  = (const float*)d_in[2];
    const float* W1    = (const float*)d_in[3];
    const float* b1    = (const float*)d_in[4];
    const float* W2    = (const float*)d_in[5];
    const float* b2    = (const float*)d_in[6];
    const float* Wout  = (const float*)d_in[7];
    const float* bout  = (const float*)d_in[8];
    float* out = (float*)d_out;

    short* p1ws = (short*)d_ws;                      // 2*192*32 bf16
    short* p2ws = p1ws + BATCH * SEQ * CDIM;         // 2*192*32 bf16
    short* wkbf = p2ws + BATCH * SEQ * CDIM;         // 128*1024 bf16

    opm_pre<<<SEQ * BATCH, 128, 0, stream>>>(p, gamma, beta, W1, b1, W2, b2,
                                             Wout, p1ws, p2ws, wkbf);
    opm_main<<<BATCH * CI * 6, 256, 0, stream>>>(p1ws, p2ws, wkbf, bout, out);
}